// Round 14
// baseline (6321.832 us; speedup 1.0000x reference)
//
#include <hip/hip_runtime.h>

#define BB   128   // batch
#define TT   1024  // time steps
#define INP  256   // input dim
#define HH   512   // hidden dim
#define OUTD 256   // output dim
#define GB   16    // batches per group (group = XCD)
#define NG   8     // groups = XCDs
#define NBLK 256   // 1 per CU (88KB LDS cap) -> bijection -> 32 blocks/XCD

typedef float  f32x4  __attribute__((ext_vector_type(4)));
typedef short  short8 __attribute__((ext_vector_type(8)));
typedef unsigned long long u64;

__device__ __forceinline__ unsigned short bf16_rne(float f) {
  union { float f; unsigned u; } v; v.f = f;
  unsigned r = v.u + 0x7fffu + ((v.u >> 16) & 1u);
  return (unsigned short)(r >> 16);
}

// tanh(x) = 1 - 2/(e^{2x}+1) via v_exp_f32 + v_rcp_f32. Abs err ~1e-7,
// far below the bf16 h-state quantization already in the pipeline.
__device__ __forceinline__ float fast_tanh(float x) {
  float t = __builtin_amdgcn_exp2f(x * 2.8853900817779268f); // 2*log2(e)
  return 1.0f - 2.0f * __builtin_amdgcn_rcpf(t + 1.0f);
}

__device__ __forceinline__ short8 pack8(f32x4 a, f32x4 b) {
  union { unsigned short s[8]; short8 v; } u;
  u.s[0] = bf16_rne(a[0]); u.s[1] = bf16_rne(a[1]);
  u.s[2] = bf16_rne(a[2]); u.s[3] = bf16_rne(a[3]);
  u.s[4] = bf16_rne(b[0]); u.s[5] = bf16_rne(b[1]);
  u.s[6] = bf16_rne(b[2]); u.s[7] = bf16_rne(b[3]);
  return u.v;
}

__device__ __forceinline__ short8 load_cvt8(const float* p) {
  const f32x4* q = (const f32x4*)p;
  return pack8(q[0], q[1]);
}

__device__ __forceinline__ f32x4 ntload4(const float* p) {
  return __builtin_nontemporal_load((const f32x4*)p);
}

// XCD-local L2 h-state load: agent-scope RELAXED atomic -> sc0 (L1 bypass),
// compiler batches many outstanding loads under one waitcnt.
__device__ __forceinline__ short8 l2load8(const unsigned short* p) {
  union { u64 q[2]; short8 v; } u;
  const u64* pp = (const u64*)p;
  u.q[0] = __hip_atomic_load(pp,     __ATOMIC_RELAXED, __HIP_MEMORY_SCOPE_AGENT);
  u.q[1] = __hip_atomic_load(pp + 1, __ATOMIC_RELAXED, __HIP_MEMORY_SCOPE_AGENT);
  return u.v;
}

// h-state fragment slots: per (slot, group): [kb(16)][lane(64)][e(8)] bf16 = 16KB.
// Value (b_local, j): kb = j>>5, lane' = ((j>>3)&3)*16 + b_local, e = j&7.
// 4-slot rings. PER-WAVE flag scheme slot-safety (wave w publishes t+2 after
// ITS 16 rows of tick t are stored+drained):
//  - h0 slot t&3 overwritten at L0 tick t; prior readers (tick t-3: L0+L1).
//    L0 gate needs L0 lines >= t+1 (done t-1) and L1 lines >= t-1 (done t-3). OK
//  - h1 slot (t+3)&3 overwritten at L1 tick t; prior reader L1 tick t-3;
//    gate A needs L1 lines >= t+1 (done t-1). OK
__device__ __forceinline__ unsigned short* hslot(unsigned short* base, int slot, int g) {
  return base + ((size_t)(slot * NG + g)) * (16 * 64 * 8);
}

__global__ void __launch_bounds__(256, 1) rnn_mfma(
    const float* __restrict__ x,       // [B][T][IN]
    const float* __restrict__ h0init,  // [2][B][H]
    const float* __restrict__ w_ih0,   // [H][IN]
    const float* __restrict__ w_hh0,   // [H][H]
    const float* __restrict__ b_ih0,   // [H]
    const float* __restrict__ b_hh0,   // [H]
    const float* __restrict__ w_ih1,   // [H][H]
    const float* __restrict__ w_hh1,   // [H][H]
    const float* __restrict__ b_ih1,   // [H]
    const float* __restrict__ b_hh1,   // [H]
    const float* __restrict__ fc_w,    // [OUT][H]
    const float* __restrict__ fc_b,    // [OUT]
    float* __restrict__ out,           // [B][OUT]
    unsigned* __restrict__ ws_ctl,     // tickets: [g*32]; flags: +1024 u32, per group 64 lines x 128B
    unsigned short* __restrict__ h0f,  // h0 ring: 4 slots x NG x 16KB
    unsigned short* __restrict__ h1f)  // h1 ring: 4 slots x NG x 16KB
{
  extern __shared__ char lds_pad[];    // 88KB dynamic -> occupancy cap (1 block/CU)
  (void)lds_pad;
  const int tid = threadIdx.x;

  // ---- claim a role on THIS XCD.
  __shared__ unsigned sh_tk, sh_g;
  if (tid == 0) {
    unsigned xcc;
    asm volatile("s_getreg_b32 %0, hwreg(HW_REG_XCC_ID)" : "=s"(xcc));
    xcc &= 7;
    sh_g  = xcc;
    sh_tk = __hip_atomic_fetch_add(ws_ctl + xcc * 32, 1u,
                                   __ATOMIC_RELAXED, __HIP_MEMORY_SCOPE_AGENT);
  }
  __syncthreads();
  const unsigned ticket = sh_tk;
  const int g = (int)sh_g;
  if (ticket >= 16) return;            // spares exit

  const int role = (int)ticket;        // 0..7: L0 j-slices; 8..15: L1 j-slices
  const bool isL0 = role < 8;
  const int wv   = tid >> 6;
  const int lane = tid & 63;
  const int ln   = lane & 15;
  const int q    = lane >> 4;
  const int j0   = (role & 7) * 64 + wv * 16 + ln;  // weight-frag row (m = lane&15)
  const int jq   = (role & 7) * 64 + wv * 16 + q * 4; // this thread's 4 output j's
  const int bg   = g * GB;

  // Per-WAVE flag lines: L0 lines [0,32) = role*4+wv; L1 lines [32,64).
  // Line b = 1 after init; = t+2 after wave completes its rows of tick t.
  volatile int* flags  = (volatile int*)(ws_ctl + 1024 + g * 2048);
  const int myline = isL0 ? (role * 4 + wv) : (32 + (role - 8) * 4 + wv);
  volatile int* myflag = flags + myline * 32;

  // ---- init: h0init -> h0 slot 3, h1init -> h1 slot 3 (redundant identical
  // writes across blocks: benign). Barrier drains the whole block's init
  // stores; each wave then publishes its line.
  for (int c = tid; c < 2048; c += 256) {
    int a  = c >> 10;
    int bl = (c >> 6) & 15;
    int j8 = (c & 63) * 8;
    short8 v = load_cvt8(h0init + ((size_t)a * BB + (bg + bl)) * HH + j8);
    unsigned short* dst = hslot(a ? h1f : h0f, 3, g)
        + ((size_t)((j8 >> 5) * 64 + ((j8 >> 3) & 3) * 16 + bl)) * 8;
    *(short8*)dst = v;
  }
  __syncthreads();                     // drain init stores to L2
  if (lane == 0) *myflag = 1;          // per-wave init publish

  // ---- weight fragments -> registers (MFMA A-operand; row j0, k = kb*32+q*8+e).
  short8 Bf0[24];  // L0: w_ih0 (kb 0..7) then w_hh0 (kb 8..23)
  short8 Bf1[32];  // L1: w_ih1 (kb 0..15) then w_hh1 (kb 16..31)
  if (isL0) {
#pragma unroll
    for (int kb = 0; kb < 24; ++kb) {
      int k = kb * 32 + q * 8;
      const float* src = (k < INP) ? (w_ih0 + (size_t)j0 * INP + k)
                                   : (w_hh0 + (size_t)j0 * HH + (k - INP));
      Bf0[kb] = load_cvt8(src);
    }
  } else {
#pragma unroll
    for (int kb = 0; kb < 32; ++kb) {
      int k = kb * 32 + q * 8;
      const float* src = (k < HH) ? (w_ih1 + (size_t)j0 * HH + k)
                                  : (w_hh1 + (size_t)j0 * HH + (k - HH));
      Bf1[kb] = load_cvt8(src);
    }
  }
  // Per-thread bias vector for its 4 output j's (jq+0..3). 16B-aligned loads.
  f32x4 bias4;
  {
    const float* bi = isL0 ? b_ih0 : b_ih1;
    const float* bh = isL0 ? b_hh0 : b_hh1;
    bias4 = *(const f32x4*)(bi + jq) + *(const f32x4*)(bh + jq);
  }

  short8 xa[8];
  if (isL0) {
    const float* xp = x + ((size_t)(bg + ln) * TT + 0) * INP;
#pragma unroll
    for (int kb = 0; kb < 8; ++kb)
      xa[kb] = pack8(ntload4(xp + kb * 32 + q * 8), ntload4(xp + kb * 32 + q * 8 + 4));
  }

  const f32x4 z = {0.f, 0.f, 0.f, 0.f};
  const int tmax = isL0 ? (TT - 1) : TT;

  // ---- tick loop: per-wave agents, NO barriers. Tick tail ordering exploits
  // in-order vmcnt: gate -> Af -> MFMA -> store -> vmcnt(0) (cheap: only
  // Af+store outstanding) -> publish -> sched_barrier -> x(t+1) load+pack
  // (HBM latency + ~130-op pack burst land AFTER publish, absorbed in the
  // inter-tick window; next poll starts with an empty vmem queue).
#pragma unroll 1
  for (int t = 0; t <= tmax; ++t) {
    if (isL0) {
      // per-wave gate: L0 lines >= t+1 (rendezvous), L1 lines >= t-1 (slot
      // guard). lane -> line lane (L0: 0..31, L1: 32..63). s_sleep backoff
      // bounds flag-line L2 traffic (R13: busy-spin x256 lanes regressed).
      {
        volatile int* fp = flags + lane * 32;
        const int thr = (lane < 32) ? (t + 1) : (t - 1);
        while (!__all(*fp >= thr)) __builtin_amdgcn_s_sleep(1);
        asm volatile("" ::: "memory");   // pin Af loads below the gate
      }

      const unsigned short* hp0 = hslot(h0f, (t + 3) & 3, g);  // h0(t-1)
      short8 Af[16];
#pragma unroll
      for (int kb = 0; kb < 16; ++kb)
        Af[kb] = l2load8(hp0 + ((size_t)kb * 64 + lane) * 8);

      f32x4 ac[4] = {z, z, z, z};
#pragma unroll
      for (int kb = 0; kb < 8; ++kb)   // x part first: runs while Af in flight
        ac[kb & 3] = __builtin_amdgcn_mfma_f32_16x16x32_bf16(
            Bf0[kb], xa[kb], ac[kb & 3], 0, 0, 0);
#pragma unroll
      for (int kb = 8; kb < 24; ++kb)
        ac[kb & 3] = __builtin_amdgcn_mfma_f32_16x16x32_bf16(
            Bf0[kb], Af[kb - 8], ac[kb & 3], 0, 0, 0);

      f32x4 d = ac[0] + ac[1] + ac[2] + ac[3];
      // D[m = q*4+r][n = ln]: 4 consecutive j (jq..jq+3), batch = ln.
      unsigned short* wdst = hslot(h0f, t & 3, g);
      union { unsigned short s[4]; u64 q8; } uu;
#pragma unroll
      for (int r = 0; r < 4; ++r)
        uu.s[r] = bf16_rne(fast_tanh(d[r] + bias4[r]));
      *(u64*)(wdst + (size_t)((jq >> 5) * 64 + ((jq >> 3) & 3) * 16 + ln) * 8
              + (jq & 7)) = uu.q8;
      asm volatile("s_waitcnt vmcnt(0)" ::: "memory");  // drain store (queue clean)
      if (lane == 0) *myflag = t + 2;                   // EARLY per-wave publish
      __builtin_amdgcn_sched_barrier(0);                // keep tail below publish

      if (t + 1 < TT) {                // x(t+1): HBM load + pack OFF-CHAIN
        const float* xp = x + ((size_t)(bg + ln) * TT + (t + 1)) * INP;
#pragma unroll
        for (int kb = 0; kb < 8; ++kb)
          xa[kb] = pack8(ntload4(xp + kb * 32 + q * 8),
                         ntload4(xp + kb * 32 + q * 8 + 4));
      }
    } else {
      // per-wave gate A: h1(t-2) ready (one tick stale -> ~no spin).
      {
        volatile int* fp = flags + (32 + (lane & 31)) * 32;
        while (!__all(*fp >= t + 1)) __builtin_amdgcn_s_sleep(1);
        asm volatile("" ::: "memory");
      }
      short8 Af1[16];
      if (t >= 1) {                    // Af1 issued early: hides under gate B
        const unsigned short* hp1 = hslot(h1f, (t + 2) & 3, g);
#pragma unroll
        for (int kb = 0; kb < 16; ++kb)
          Af1[kb] = l2load8(hp1 + ((size_t)kb * 64 + lane) * 8);
      }
      // per-wave gate B: h0(t-1) ready — the real rendezvous.
      {
        volatile int* fp = flags + (lane & 31) * 32;
        while (!__all(*fp >= t + 1)) __builtin_amdgcn_s_sleep(1);
        asm volatile("" ::: "memory");
      }

      if (t >= 1) {
        const unsigned short* hp0 = hslot(h0f, (t + 3) & 3, g);  // h0(t-1)
        short8 Af0[16];
#pragma unroll
        for (int kb = 0; kb < 16; ++kb)
          Af0[kb] = l2load8(hp0 + ((size_t)kb * 64 + lane) * 8);

        f32x4 ac[4] = {z, z, z, z};
#pragma unroll
        for (int kb = 0; kb < 16; ++kb)  // h1 part first: Af1 ready, Af0 in flight
          ac[kb & 3] = __builtin_amdgcn_mfma_f32_16x16x32_bf16(
              Bf1[kb + 16], Af1[kb], ac[kb & 3], 0, 0, 0);
#pragma unroll
        for (int kb = 0; kb < 16; ++kb)
          ac[kb & 3] = __builtin_amdgcn_mfma_f32_16x16x32_bf16(
              Bf1[kb], Af0[kb], ac[kb & 3], 0, 0, 0);

        f32x4 d = ac[0] + ac[1] + ac[2] + ac[3];
        unsigned short* wdst = hslot(h1f, (t + 3) & 3, g);  // h1(t-1)
        union { unsigned short s[4]; u64 q8; } uu;
#pragma unroll
        for (int r = 0; r < 4; ++r)
          uu.s[r] = bf16_rne(fast_tanh(d[r] + bias4[r]));
        *(u64*)(wdst + (size_t)((jq >> 5) * 64 + ((jq >> 3) & 3) * 16 + ln) * 8
                + (jq & 7)) = uu.q8;
      }
      asm volatile("s_waitcnt vmcnt(0)" ::: "memory");
      if (lane == 0) *myflag = t + 2;   // per-wave publish
    }
  }

  // ---- FC epilogue: out = h1(TT-1) @ fc_w^T + fc_b (slot 3). Wait for all
  // L1 wave lines to reach TT+2 (final h1 stored+drained).
  if (wv == 0) {
    {
      volatile int* fp = flags + (32 + (lane & 31)) * 32;
      while (!__all(*fp >= TT + 2)) {}
      asm volatile("" ::: "memory");
    }
    const unsigned short* hp = hslot(h1f, 3, g);
    const int o_ln = role * 16 + ln;      // fc_w frag row (A-operand, m = ln)
    const int o_q  = role * 16 + q * 4;   // this thread's 4 output cols
    f32x4 ac[4] = {z, z, z, z};
#pragma unroll
    for (int kb = 0; kb < 16; ++kb) {
      int k = kb * 32 + q * 8;
      short8 Bfc = load_cvt8(fc_w + (size_t)o_ln * HH + k);
      short8 Af  = l2load8(hp + ((size_t)kb * 64 + lane) * 8);
      ac[kb & 3] = __builtin_amdgcn_mfma_f32_16x16x32_bf16(
          Bfc, Af, ac[kb & 3], 0, 0, 0);
    }
    // D[m = q*4+r][n = ln]: out[bg+ln][o_q + r] -> one 16B coalesced store.
    f32x4 fb = *(const f32x4*)(fc_b + o_q);
    f32x4 v = ac[0] + ac[1] + ac[2] + ac[3] + fb;
    *(f32x4*)(out + (size_t)(bg + ln) * OUTD + o_q) = v;
  }
}

extern "C" void kernel_launch(void* const* d_in, const int* in_sizes, int n_in,
                              void* d_out, int out_size, void* d_ws, size_t ws_size,
                              hipStream_t stream) {
  (void)in_sizes; (void)n_in; (void)out_size; (void)ws_size;

  const float* x      = (const float*)d_in[0];
  const float* h0init = (const float*)d_in[1];
  const float* w_ih0  = (const float*)d_in[2];
  const float* w_hh0  = (const float*)d_in[3];
  const float* b_ih0  = (const float*)d_in[4];
  const float* b_hh0  = (const float*)d_in[5];
  const float* w_ih1  = (const float*)d_in[6];
  const float* w_hh1  = (const float*)d_in[7];
  const float* b_ih1  = (const float*)d_in[8];
  const float* b_hh1  = (const float*)d_in[9];
  const float* fc_w   = (const float*)d_in[10];
  const float* fc_b   = (const float*)d_in[11];
  float* out = (float*)d_out;

  // ws: [0,131072) tickets + per-wave flags (zeroed); then h0 ring 512KB; h1 ring 512KB
  unsigned* ws_ctl = (unsigned*)d_ws;
  unsigned short* h0f = (unsigned short*)((char*)d_ws + 131072);
  unsigned short* h1f = h0f + 4 * NG * (16 * 64 * 8);

  hipMemsetAsync(d_ws, 0, 131072, stream);

  rnn_mfma<<<dim3(NBLK), dim3(256), 90112, stream>>>(
      x, h0init, w_ih0, w_hh0, b_ih0, b_hh0, w_ih1, w_hh1, b_ih1, b_hh1,
      fc_w, fc_b, out, ws_ctl, h0f, h1f);
}

// Round 16
// 3482.726 us; speedup vs baseline: 1.8152x; 1.8152x over previous
//
#include <hip/hip_runtime.h>

#define BB   128   // batch
#define TT   1024  // time steps
#define INP  256   // input dim
#define HH   512   // hidden dim
#define OUTD 256   // output dim
#define GB   16    // batches per group (group = XCD)
#define NG   8     // groups = XCDs
#define NBLK 256   // 1 per CU (88KB LDS cap); 16 consumers + 4 producers per XCD

typedef float  f32x4  __attribute__((ext_vector_type(4)));
typedef short  short8 __attribute__((ext_vector_type(8)));
typedef unsigned long long u64;

__device__ __forceinline__ unsigned short bf16_rne(float f) {
  union { float f; unsigned u; } v; v.f = f;
  unsigned r = v.u + 0x7fffu + ((v.u >> 16) & 1u);
  return (unsigned short)(r >> 16);
}

// tanh(x) = 1 - 2/(e^{2x}+1) via v_exp_f32 + v_rcp_f32. Abs err ~1e-7.
__device__ __forceinline__ float fast_tanh(float x) {
  float t = __builtin_amdgcn_exp2f(x * 2.8853900817779268f); // 2*log2(e)
  return 1.0f - 2.0f * __builtin_amdgcn_rcpf(t + 1.0f);
}

__device__ __forceinline__ short8 pack8(f32x4 a, f32x4 b) {
  union { unsigned short s[8]; short8 v; } u;
  u.s[0] = bf16_rne(a[0]); u.s[1] = bf16_rne(a[1]);
  u.s[2] = bf16_rne(a[2]); u.s[3] = bf16_rne(a[3]);
  u.s[4] = bf16_rne(b[0]); u.s[5] = bf16_rne(b[1]);
  u.s[6] = bf16_rne(b[2]); u.s[7] = bf16_rne(b[3]);
  return u.v;
}

__device__ __forceinline__ short8 load_cvt8(const float* p) {
  const f32x4* q = (const f32x4*)p;
  return pack8(q[0], q[1]);
}

__device__ __forceinline__ f32x4 ntload4(const float* p) {
  return __builtin_nontemporal_load((const f32x4*)p);
}

// XCD-local L2 load: agent-scope RELAXED atomic -> sc0 (L1 bypass).
__device__ __forceinline__ short8 l2load8(const unsigned short* p) {
  union { u64 q[2]; short8 v; } u;
  const u64* pp = (const u64*)p;
  u.q[0] = __hip_atomic_load(pp,     __ATOMIC_RELAXED, __HIP_MEMORY_SCOPE_AGENT);
  u.q[1] = __hip_atomic_load(pp + 1, __ATOMIC_RELAXED, __HIP_MEMORY_SCOPE_AGENT);
  return u.v;
}

__device__ __forceinline__ f32x4 l2load4f(const float* p) {
  union { u64 q[2]; f32x4 v; } u;
  const u64* pp = (const u64*)p;
  u.q[0] = __hip_atomic_load(pp,     __ATOMIC_RELAXED, __HIP_MEMORY_SCOPE_AGENT);
  u.q[1] = __hip_atomic_load(pp + 1, __ATOMIC_RELAXED, __HIP_MEMORY_SCOPE_AGENT);
  return u.v;
}

// h-state fragment slots: per (slot, group): [kb(16)][lane(64)][e(8)] bf16 = 16KB.
// 4-slot rings; R6-proven consumer flag scheme (16 lines/group) + 4 producer
// lines (16..19). u0 ring: 4 slots x NG x 32KB f32; slot shared by 4
// producers, each owning a 128-j slice of EVERY tick (register-safe: 16
// weight frags = 64 VGPR/thread, vs 256 for whole-tick ownership).
// Slot-safety: h0 slot t&3 overwrite guarded by L0>=t+1, L1>=t-1 (R6 proven);
// u0 slot t&3 overwrite guarded by producer waiting L0 flags >= t-2 (readers
// of u0(t-4) = L0 tick t-4 are done). No cycle: producer t needs L0 t-4;
// L0 t-4 needs producer t-4; grounds out at t<4 (thresholds trivial).
__device__ __forceinline__ unsigned short* hslot(unsigned short* base, int slot, int g) {
  return base + ((size_t)(slot * NG + g)) * (16 * 64 * 8);
}

__global__ void __launch_bounds__(256, 1) rnn_mfma(
    const float* __restrict__ x,       // [B][T][IN]
    const float* __restrict__ h0init,  // [2][B][H]
    const float* __restrict__ w_ih0,   // [H][IN]
    const float* __restrict__ w_hh0,   // [H][H]
    const float* __restrict__ b_ih0,   // [H]
    const float* __restrict__ b_hh0,   // [H]
    const float* __restrict__ w_ih1,   // [H][H]
    const float* __restrict__ w_hh1,   // [H][H]
    const float* __restrict__ b_ih1,   // [H]
    const float* __restrict__ b_hh1,   // [H]
    const float* __restrict__ fc_w,    // [OUT][H]
    const float* __restrict__ fc_b,    // [OUT]
    float* __restrict__ out,           // [B][OUT]
    unsigned* __restrict__ ws_ctl,     // tickets [g*32]; flags +1024 u32, per group 1024 u32 (20 lines x 32)
    unsigned short* __restrict__ h0f,  // h0 ring: 4 slots x NG x 16KB
    unsigned short* __restrict__ h1f,  // h1 ring: 4 slots x NG x 16KB
    float* __restrict__ u0r)           // u0 ring: 4 slots x NG x 32KB
{
  extern __shared__ char lds_pad[];    // 88KB dynamic -> 1 block/CU
  (void)lds_pad;
  const int tid = threadIdx.x;

  // ---- claim a role on THIS XCD.
  __shared__ unsigned sh_tk, sh_g;
  if (tid == 0) {
    unsigned xcc;
    asm volatile("s_getreg_b32 %0, hwreg(HW_REG_XCC_ID)" : "=s"(xcc));
    xcc &= 7;
    sh_g  = xcc;
    sh_tk = __hip_atomic_fetch_add(ws_ctl + xcc * 32, 1u,
                                   __ATOMIC_RELAXED, __HIP_MEMORY_SCOPE_AGENT);
  }
  __syncthreads();
  const unsigned ticket = sh_tk;
  const int g = (int)sh_g;
  if (ticket >= 20) return;            // spares exit

  const int wv   = tid >> 6;
  const int lane = tid & 63;
  const int ln   = lane & 15;
  const int q    = lane >> 4;
  const int bg   = g * GB;
  volatile int* flags = (volatile int*)(ws_ctl + 1024 + g * 1024);
  const f32x4 z = {0.f, 0.f, 0.f, 0.f};

  if (ticket >= 16) {
    // ========== PRODUCER (4 per XCD): u0[:, jslice] = x(t) @ w_ih0^T =======
    // prod p owns j in [p*128, (p+1)*128) of EVERY tick. Off the critical
    // cycle: HBM latency + pack8 burst land here, not in consumers.
    const int prod = (int)ticket - 16;
    // wave wv covers j in [p*128 + wv*32, +32): 2 j-tiles x 8 kb = 16 frags.
    short8 Wp[16];
#pragma unroll
    for (int jt = 0; jt < 2; ++jt)
#pragma unroll
      for (int kb = 0; kb < 8; ++kb)
        Wp[jt * 8 + kb] = load_cvt8(
            w_ih0 + (size_t)(prod * 128 + wv * 32 + jt * 16 + ln) * INP
            + kb * 32 + q * 8);
    volatile int* pf = flags + (16 + prod) * 32;

#pragma unroll 1
    for (int t = 0; t < TT; ++t) {
      // backpressure: readers of u0(t-4) (L0 tick t-4) done -> L0 flags >= t-2.
      if (tid < 8) {
        volatile int* fp = flags + tid * 32;
        const int thr = t - 2;
        while (*fp < thr) __builtin_amdgcn_s_sleep(1);
      }
      __syncthreads();

      short8 xa[8];
      const float* xp = x + ((size_t)(bg + ln) * TT + t) * INP;
#pragma unroll
      for (int kb = 0; kb < 8; ++kb)
        xa[kb] = pack8(ntload4(xp + kb * 32 + q * 8),
                       ntload4(xp + kb * 32 + q * 8 + 4));

      f32x4 acc[2] = {z, z};
#pragma unroll
      for (int jt = 0; jt < 2; ++jt)
#pragma unroll
        for (int kb = 0; kb < 8; ++kb)
          acc[jt] = __builtin_amdgcn_mfma_f32_16x16x32_bf16(
              Wp[jt * 8 + kb], xa[kb], acc[jt], 0, 0, 0);

      // D[m=q*4+r][n=ln]: j = p*128 + wv*32 + jt*16 + q*4 + r, b = ln.
      // f32x4 store at ((j>>2)*16 + b)*4 floats; j>>2 = p*32+wv*8+jt*4+q.
      float* slotbase = u0r + ((size_t)((t & 3) * NG + g)) * 8192;
#pragma unroll
      for (int jt = 0; jt < 2; ++jt)
        *(f32x4*)(slotbase
            + ((size_t)((prod * 32 + wv * 8 + jt * 4 + q) * 16 + ln)) * 4) = acc[jt];
      __syncthreads();                 // drain u0 stores to L2
      if (tid == 0) *pf = t + 2;       // publish u0(t) slice
    }
    return;
  }

  // ================= CONSUMERS (16 per XCD): R6 structure =================
  const int role = (int)ticket;        // 0..7: L0 j-slices; 8..15: L1 j-slices
  const bool isL0 = role < 8;
  const int j0   = (role & 7) * 64 + wv * 16 + ln;  // weight-frag row
  const int jq   = (role & 7) * 64 + wv * 16 + q * 4;
  volatile int* myflag = flags + role * 32;

  // ---- init: h0init -> h0 slot 3, h1init -> h1 slot 3.
  for (int c = tid; c < 2048; c += 256) {
    int a  = c >> 10;
    int bl = (c >> 6) & 15;
    int j8 = (c & 63) * 8;
    short8 v = load_cvt8(h0init + ((size_t)a * BB + (bg + bl)) * HH + j8);
    unsigned short* dst = hslot(a ? h1f : h0f, 3, g)
        + ((size_t)((j8 >> 5) * 64 + ((j8 >> 3) & 3) * 16 + bl)) * 8;
    *(short8*)dst = v;
  }
  __syncthreads();                     // drain init stores to L2
  if (tid == 0) *myflag = 1;           // init published

  // ---- weight fragments (MFMA A-operand; row j0, k = kb*32+q*8+e).
  short8 Bf0[16];  // L0: w_hh0 only (x part moved to producers)
  short8 Bf1[32];  // L1: w_ih1 (kb 0..15) then w_hh1 (kb 16..31)
  if (isL0) {
#pragma unroll
    for (int kb = 0; kb < 16; ++kb)
      Bf0[kb] = load_cvt8(w_hh0 + (size_t)j0 * HH + kb * 32 + q * 8);
  } else {
#pragma unroll
    for (int kb = 0; kb < 32; ++kb) {
      int k = kb * 32 + q * 8;
      const float* src = (k < HH) ? (w_ih1 + (size_t)j0 * HH + k)
                                  : (w_hh1 + (size_t)j0 * HH + (k - HH));
      Bf1[kb] = load_cvt8(src);
    }
  }
  f32x4 bias4;
  {
    const float* bi = isL0 ? b_ih0 : b_ih1;
    const float* bh = isL0 ? b_hh0 : b_hh1;
    bias4 = *(const f32x4*)(bi + jq) + *(const f32x4*)(bh + jq);
  }

  const int tmax = isL0 ? (TT - 1) : TT;

  // ---- tick loop (R6-proven gate structure; L0 consumes u0 from producers).
#pragma unroll 1
  for (int t = 0; t <= tmax; ++t) {
    if (isL0) {
      // gate: L0 lines >= t+1 (rendezvous), L1 >= t-1 (slot guard),
      // producer lines 16..19 >= t+2 (all 4 j-slices of u0(t) ready;
      // producers run ~4 ticks ahead -> ~no spin).
      if (tid < 16) {
        volatile int* fp = flags + tid * 32;
        const int thr = (tid < 8) ? (t + 1) : (t - 1);
        while (*fp < thr) {}
      } else if (tid < 20) {
        volatile int* fp = flags + tid * 32;
        while (*fp < t + 2) {}
      }
      __syncthreads();

      const unsigned short* hp0 = hslot(h0f, (t + 3) & 3, g);  // h0(t-1)
      short8 Af[16];
#pragma unroll
      for (int kb = 0; kb < 16; ++kb)
        Af[kb] = l2load8(hp0 + ((size_t)kb * 64 + lane) * 8);
      // u0 load issued after Af: MFMA waits only on Af (in-order vmcnt),
      // u0 completes during the MFMA chain.
      const float* up = u0r + ((size_t)((t & 3) * NG + g)) * 8192
          + ((size_t)((((role & 7) * 16 + wv * 4 + q) * 16) + ln)) * 4;
      f32x4 u0v = l2load4f(up);

      f32x4 ac[4] = {z, z, z, z};
#pragma unroll
      for (int kb = 0; kb < 16; ++kb)
        ac[kb & 3] = __builtin_amdgcn_mfma_f32_16x16x32_bf16(
            Bf0[kb], Af[kb], ac[kb & 3], 0, 0, 0);

      f32x4 d = ac[0] + ac[1] + ac[2] + ac[3] + u0v;
      unsigned short* wdst = hslot(h0f, t & 3, g);
      union { unsigned short s[4]; u64 q8; } uu;
#pragma unroll
      for (int r = 0; r < 4; ++r)
        uu.s[r] = bf16_rne(fast_tanh(d[r] + bias4[r]));
      *(u64*)(wdst + (size_t)((jq >> 5) * 64 + ((jq >> 3) & 3) * 16 + ln) * 8
              + (jq & 7)) = uu.q8;
    } else {
      // gate A: h1(t-2) ready (one tick stale -> ~no spin).
      if (tid >= 8 && tid < 16) {
        volatile int* fp = flags + tid * 32;
        while (*fp < t + 1) {}
      }
      __syncthreads();
      // Af1 issued early: latency hides under gate B's poll.
      const unsigned short* hp1 = hslot(h1f, (t + 2) & 3, g);
      short8 Af1[16];
#pragma unroll
      for (int kb = 0; kb < 16; ++kb)
        Af1[kb] = l2load8(hp1 + ((size_t)kb * 64 + lane) * 8);

      // gate B: h0(t-1) ready — the real rendezvous.
      if (tid < 8) {
        volatile int* fp = flags + tid * 32;
        while (*fp < t + 1) {}
      }
      __syncthreads();

      if (t >= 1) {
        const unsigned short* hp0 = hslot(h0f, (t + 3) & 3, g);  // h0(t-1)
        short8 Af0[16];
#pragma unroll
        for (int kb = 0; kb < 16; ++kb)
          Af0[kb] = l2load8(hp0 + ((size_t)kb * 64 + lane) * 8);

        f32x4 ac[4] = {z, z, z, z};
#pragma unroll
        for (int kb = 0; kb < 16; ++kb)  // h1 part first: Af1 ready, Af0 in flight
          ac[kb & 3] = __builtin_amdgcn_mfma_f32_16x16x32_bf16(
              Bf1[kb + 16], Af1[kb], ac[kb & 3], 0, 0, 0);
#pragma unroll
        for (int kb = 0; kb < 16; ++kb)
          ac[kb & 3] = __builtin_amdgcn_mfma_f32_16x16x32_bf16(
              Bf1[kb], Af0[kb], ac[kb & 3], 0, 0, 0);

        f32x4 d = ac[0] + ac[1] + ac[2] + ac[3];
        unsigned short* wdst = hslot(h1f, (t + 3) & 3, g);  // h1(t-1)
        union { unsigned short s[4]; u64 q8; } uu;
#pragma unroll
        for (int r = 0; r < 4; ++r)
          uu.s[r] = bf16_rne(fast_tanh(d[r] + bias4[r]));
        *(u64*)(wdst + (size_t)((jq >> 5) * 64 + ((jq >> 3) & 3) * 16 + ln) * 8
                + (jq & 7)) = uu.q8;
      }
    }

    __syncthreads();                   // drain this tick's h stores to L2
    if (tid == 0) *myflag = t + 2;     // publish tick completion
  }

  // ---- FC epilogue: out = h1(TT-1) @ fc_w^T + fc_b (slot 3).
  if (tid < 16) {
    volatile int* fp = flags + tid * 32;
    const int thr = (tid < 8) ? (TT + 1) : (TT + 2);
    while (*fp < thr) {}
  }
  __syncthreads();

  if (wv == 0) {
    const unsigned short* hp = hslot(h1f, 3, g);
    const int o_ln = role * 16 + ln;      // fc_w frag row (A-operand, m = ln)
    const int o_q  = role * 16 + q * 4;   // this thread's 4 output cols
    f32x4 ac[4] = {z, z, z, z};
#pragma unroll
    for (int kb = 0; kb < 16; ++kb) {
      int k = kb * 32 + q * 8;
      short8 Bfc = load_cvt8(fc_w + (size_t)o_ln * HH + k);
      short8 Af  = l2load8(hp + ((size_t)kb * 64 + lane) * 8);
      ac[kb & 3] = __builtin_amdgcn_mfma_f32_16x16x32_bf16(
          Bfc, Af, ac[kb & 3], 0, 0, 0);
    }
    f32x4 fb = *(const f32x4*)(fc_b + o_q);
    f32x4 v = ac[0] + ac[1] + ac[2] + ac[3] + fb;
    *(f32x4*)(out + (size_t)(bg + ln) * OUTD + o_q) = v;
  }
}

extern "C" void kernel_launch(void* const* d_in, const int* in_sizes, int n_in,
                              void* d_out, int out_size, void* d_ws, size_t ws_size,
                              hipStream_t stream) {
  (void)in_sizes; (void)n_in; (void)out_size; (void)ws_size;

  const float* x      = (const float*)d_in[0];
  const float* h0init = (const float*)d_in[1];
  const float* w_ih0  = (const float*)d_in[2];
  const float* w_hh0  = (const float*)d_in[3];
  const float* b_ih0  = (const float*)d_in[4];
  const float* b_hh0  = (const float*)d_in[5];
  const float* w_ih1  = (const float*)d_in[6];
  const float* w_hh1  = (const float*)d_in[7];
  const float* b_ih1  = (const float*)d_in[8];
  const float* b_hh1  = (const float*)d_in[9];
  const float* fc_w   = (const float*)d_in[10];
  const float* fc_b   = (const float*)d_in[11];
  float* out = (float*)d_out;

  // ws layout: [0,64K) tickets+flags (zeroed); h0 ring 512KB @64K;
  // h1 ring 512KB; u0 ring 1MB. Total ~2.1MB.
  unsigned* ws_ctl = (unsigned*)d_ws;
  unsigned short* h0f = (unsigned short*)((char*)d_ws + 65536);
  unsigned short* h1f = h0f + 4 * NG * (16 * 64 * 8);
  float* u0r = (float*)((char*)d_ws + 65536 + 2 * 4 * NG * (16 * 64 * 8) * 2);

  hipMemsetAsync(d_ws, 0, 65536, stream);

  rnn_mfma<<<dim3(NBLK), dim3(256), 90112, stream>>>(
      x, h0init, w_ih0, w_hh0, b_ih0, b_hh0, w_ih1, w_hh1, b_ih1, b_hh1,
      fc_w, fc_b, out, ws_ctl, h0f, h1f, u0r);
}